// Round 6
// baseline (1171.004 us; speedup 1.0000x reference)
//
#include <hip/hip_runtime.h>
#include <math.h>

#define H 2048
#define IDIM 5632
#define NE 8
#define TT 2048            // tokens = 2*1024
#define LDW1 (2 * IDIM)    // 11264
#define NK1 (H / 64)       // 32
#define NK2 (IDIM / 64)    // 88

typedef __bf16 bf16x8 __attribute__((ext_vector_type(8)));
typedef float f32x4 __attribute__((ext_vector_type(4)));

__device__ __forceinline__ unsigned short f2bf(float f) {
    unsigned int u = __builtin_bit_cast(unsigned int, f);
    u += 0x7FFFu + ((u >> 16) & 1u);   // round-to-nearest-even
    return (unsigned short)(u >> 16);
}

// HW convert: compiler emits v_cvt_pk_bf16_f32 from paired casts (RTNE)
__device__ __forceinline__ unsigned int pk2(float a, float b) {
    __bf16 x = (__bf16)a, y = (__bf16)b;
    unsigned short lo = __builtin_bit_cast(unsigned short, x);
    unsigned short hi = __builtin_bit_cast(unsigned short, y);
    return (unsigned int)lo | ((unsigned int)hi << 16);
}

__device__ __forceinline__ void gload_lds16(const void* g, void* l) {
    __builtin_amdgcn_global_load_lds(
        (const __attribute__((address_space(1))) void*)g,
        (__attribute__((address_space(3))) void*)l, 16, 0, 0);
}

#define WAITCNT_FENCE(str)                         \
    asm volatile(str ::: "memory");                \
    __builtin_amdgcn_sched_barrier(0);             \
    __builtin_amdgcn_s_barrier();                  \
    __builtin_amdgcn_sched_barrier(0);

// ---------------- x (fp32) -> bf16 ----------------
__global__ void cvt_x_kernel(const float* __restrict__ x, unsigned short* __restrict__ xb) {
    int i = blockIdx.x * blockDim.x + threadIdx.x;
    float4 v = reinterpret_cast<const float4*>(x)[i];
    ushort4 o;
    o.x = f2bf(v.x); o.y = f2bf(v.y); o.z = f2bf(v.z); o.w = f2bf(v.w);
    reinterpret_cast<ushort4*>(xb)[i] = o;
}

// ---------------- router: fp64 logits, softmax, top-2, lists ----------------
__global__ void router_kernel(const float* __restrict__ x, const float* __restrict__ gw,
                              float* __restrict__ topw, int* __restrict__ cnt,
                              int* __restrict__ list) {
    int t = blockIdx.x;
    int lane = threadIdx.x;
    const float* xt = x + (size_t)t * H;
    double acc[NE];
#pragma unroll
    for (int e = 0; e < NE; ++e) acc[e] = 0.0;
    for (int h = lane; h < H; h += 64) {
        float xv = xt[h];
#pragma unroll
        for (int e = 0; e < NE; ++e) acc[e] += (double)xv * (double)gw[e * H + h];
    }
#pragma unroll
    for (int e = 0; e < NE; ++e) {
#pragma unroll
        for (int off = 32; off > 0; off >>= 1)
            acc[e] += __shfl_xor(acc[e], off, 64);
    }
    if (lane == 0) {
        double mx = acc[0];
#pragma unroll
        for (int e = 1; e < NE; ++e) mx = acc[e] > mx ? acc[e] : mx;
        double ex[NE], s = 0.0;
#pragma unroll
        for (int e = 0; e < NE; ++e) { ex[e] = exp(acc[e] - mx); s += ex[e]; }
        int e0 = 0; double b0 = ex[0];
#pragma unroll
        for (int e = 1; e < NE; ++e) if (ex[e] > b0) { b0 = ex[e]; e0 = e; }
        int e1 = -1; double b1 = -1.0;
#pragma unroll
        for (int e = 0; e < NE; ++e) if (e != e0 && ex[e] > b1) { b1 = ex[e]; e1 = e; }
        float p0 = (float)(b0 / s), p1 = (float)(b1 / s);
        float w0 = p0 / (p0 + p1), w1 = p1 / (p0 + p1);
        topw[t * 2 + 0] = w0;
        topw[t * 2 + 1] = w1;
        int pos0 = atomicAdd(&cnt[e0], 1); list[e0 * TT + pos0] = t * 2 + 0;
        int pos1 = atomicAdd(&cnt[e1], 1); list[e1 * TT + pos1] = t * 2 + 1;
    }
}

// ---------------- tile map: group tile prefix sums (256-row tiles) ----------------
__global__ void setup_kernel(const int* __restrict__ cnt, int* __restrict__ tmap) {
    if (threadIdx.x == 0) {
        int acc0 = 0;
        tmap[0] = 0;
        for (int g = 0; g < 9; ++g) {
            int rows = (g == 0) ? TT : cnt[g - 1];
            tmap[10 + g] = rows;
            acc0 += (rows + 255) >> 8;
            tmap[g + 1] = acc0;
        }
        tmap[19] = 0;
    }
}

// ============ grouped GEMM1: 256 rows x 256 wcols (=128 act cols), BK=64 ============
// A (bf16, gathered) -> global_load_lds dbuf; B (fp32 weights) -> reg prefetch 2-deep,
// cvt_pk + swizzled ds_write; one barrier per K-tile, vmcnt(8) keeps B prefetch alive.
__global__ __launch_bounds__(512, 2)
void gemm1_kernel(const unsigned short* __restrict__ xb,
                  const float* __restrict__ base_gu,
                  const float* __restrict__ exp_gu,
                  const int* __restrict__ tmap,
                  const int* __restrict__ list,
                  unsigned short* __restrict__ actB,
                  unsigned short* __restrict__ actE) {
    __shared__ unsigned short lds_a[2][256 * 64];
    __shared__ unsigned short lds_b[2][256 * 64];
    __shared__ int s_arow[256];
    __shared__ int s_orow[256];
    __shared__ int sh[20];

    int tid = threadIdx.x;
    if (tid < 20) sh[tid] = tmap[tid];
    __syncthreads();
    int bid = blockIdx.x;
    int virt = (bid & 7) * 176 + (bid >> 3);     // 1408 = 8*176, XCD-contiguous cols
    int jcol = virt >> 5;                        // 0..43
    int rt = virt & 31;
    if (rt >= sh[9]) return;
    int g = 0;
    while (rt >= sh[g + 1]) ++g;
    int rows_g = sh[10 + g];
    int row0 = (rt - sh[g]) * 256;
    int n0a = jcol * 128;                        // act-col base

    if (tid < 256) {
        int r = row0 + tid;
        int arow = 0, orow = 0;
        if (r < rows_g) {
            if (g == 0) { arow = r; orow = r; }
            else { int e = list[(g - 1) * TT + r]; arow = e >> 1; orow = e; }
        }
        s_arow[tid] = arow;
        s_orow[tid] = orow;
    }
    __syncthreads();

    const float* W = (g == 0) ? base_gu : (exp_gu + (size_t)(g - 1) * H * LDW1);
    unsigned short* actPtr = (g == 0) ? actB : actE;

    // ---- A staging: issue i covers rows i*64..+63; thread -> row_l=tid>>3, kc=tid&7
    int arow_l = tid >> 3;                       // 0..63
    int akc = tid & 7;
    int asw = akc ^ (arow_l & 7);
    const unsigned short* asrc[4];
#pragma unroll
    for (int i = 0; i < 4; ++i)
        asrc[i] = xb + (size_t)s_arow[i * 64 + arow_l] * H + asw * 8;
    int awoff = (tid >> 6) * 1024;               // wave-uniform; HW adds lane*16

    auto issueA = [&](int ktile, int buf) {
#pragma unroll
        for (int i = 0; i < 4; ++i)
            gload_lds16(asrc[i] + ktile * 64, (char*)lds_a[buf] + i * 8192 + awoff);
    };

    // ---- B staging: thread -> cols c0..c0+3 (c0=4*(tid&63)), k-rows kr*8..+7 (kr=tid>>6)
    int cg = tid & 63, kr = tid >> 6;
    int c0 = cg * 4;
    int wcol0 = (((c0 >> 5) & 1) ? IDIM : 0) + n0a + ((c0 >> 6) << 5) + (c0 & 31);
    const float* wp = W + (size_t)kr * 8 * LDW1 + wcol0;
    int bwaddr[4];
#pragma unroll
    for (int j = 0; j < 4; ++j)
        bwaddr[j] = (c0 + j) * 128 + ((kr ^ ((c0 + j) & 7)) << 4);

    auto ldB = [&](float4* dst, int ktile) {
        const float* p = wp + (size_t)(ktile * 64) * LDW1;
#pragma unroll
        for (int r = 0; r < 8; ++r)
            dst[r] = *reinterpret_cast<const float4*>(p + (size_t)r * LDW1);
    };
    auto wrB = [&](const float4* src, int buf) {
        char* pb = (char*)lds_b[buf];
#pragma unroll
        for (int j = 0; j < 4; ++j) {
            uint4 pk;
            pk.x = pk2(((const float*)&src[0])[j], ((const float*)&src[1])[j]);
            pk.y = pk2(((const float*)&src[2])[j], ((const float*)&src[3])[j]);
            pk.z = pk2(((const float*)&src[4])[j], ((const float*)&src[5])[j]);
            pk.w = pk2(((const float*)&src[6])[j], ((const float*)&src[7])[j]);
            *reinterpret_cast<uint4*>(pb + bwaddr[j]) = pk;
        }
    };

    // ---- MFMA geometry: 8 waves = 2M x 4N; per wave 128 rows x 64 cols
    int wave = tid >> 6, lane = tid & 63;
    int wr = wave >> 2, wc = wave & 3;
    int arow0 = wr * 128 + (lane & 15);
    int bcol0 = wc * 64 + (lane & 15);
    int lxor = lane & 7;
    int kq = lane >> 4;

    f32x4 acc[8][4];
#pragma unroll
    for (int fm = 0; fm < 8; ++fm)
#pragma unroll
        for (int fn = 0; fn < 4; ++fn)
            acc[fm][fn] = (f32x4)(0.0f);

    auto mfmaTile = [&](int buf) {
        const char* pa = (const char*)lds_a[buf];
        const char* pb = (const char*)lds_b[buf];
#pragma unroll
        for (int kh = 0; kh < 2; ++kh) {
            int kc = kq + kh * 4;
            int slot = (kc ^ lxor) << 4;
            bf16x8 bfr[4];
#pragma unroll
            for (int fn = 0; fn < 4; ++fn)
                bfr[fn] = *reinterpret_cast<const bf16x8*>(pb + (bcol0 + fn * 16) * 128 + slot);
#pragma unroll
            for (int fmh = 0; fmh < 2; ++fmh) {
                bf16x8 afr[4];
#pragma unroll
                for (int i = 0; i < 4; ++i)
                    afr[i] = *reinterpret_cast<const bf16x8*>(
                        pa + (arow0 + fmh * 64 + i * 16) * 128 + slot);
#pragma unroll
                for (int fn = 0; fn < 4; ++fn)
#pragma unroll
                    for (int i = 0; i < 4; ++i)
                        acc[fmh * 4 + i][fn] = __builtin_amdgcn_mfma_f32_16x16x32_bf16(
                            afr[i], bfr[fn], acc[fmh * 4 + i][fn], 0, 0, 0);
            }
        }
    };

    float4 rB0[8], rB1[8];
    // prologue: tile0 complete, B(1)+A(1) in flight
    issueA(0, 0);
    ldB(rB0, 0);
    wrB(rB0, 0);                 // compiler waits B0 (drains A0 too: A0 older)
    ldB(rB1, 1);
    issueA(1, 1);
    WAITCNT_FENCE("s_waitcnt lgkmcnt(0)")

    for (int kt = 0; kt < NK1 - 2; kt += 2) {
        // even K-tile: buf0; rB1 holds B(kt+1)
        wrB(rB1, 1);
        ldB(rB0, kt + 2);
        mfmaTile(0);
        WAITCNT_FENCE("s_waitcnt vmcnt(8) lgkmcnt(0)")
        issueA(kt + 2, 0);
        // odd K-tile: buf1; rB0 holds B(kt+2)
        wrB(rB0, 0);
        ldB(rB1, kt + 3);
        mfmaTile(1);
        WAITCNT_FENCE("s_waitcnt vmcnt(8) lgkmcnt(0)")
        issueA(kt + 3, 1);
    }
    // kt = NK-2 (buf0): rB1 = B(NK-1)
    wrB(rB1, 1);
    mfmaTile(0);
    WAITCNT_FENCE("s_waitcnt vmcnt(0) lgkmcnt(0)")
    // kt = NK-1 (buf1)
    mfmaTile(1);

    int cq = lane >> 4, cr = lane & 15;
#pragma unroll
    for (int fm = 0; fm < 8; ++fm) {
#pragma unroll
        for (int r = 0; r < 4; ++r) {
            int rloc = wr * 128 + fm * 16 + cq * 4 + r;
            if (row0 + rloc < rows_g) {
                size_t orow = (size_t)s_orow[rloc];
#pragma unroll
                for (int fn = 0; fn < 2; ++fn) {
                    float gv = acc[fm][fn][r];
                    float uv = acc[fm][fn + 2][r];
                    float sv = gv / (1.0f + __expf(-gv));
                    int col = n0a + wc * 32 + fn * 16 + cr;
                    actPtr[orow * IDIM + col] = f2bf(sv * uv);
                }
            }
        }
    }
}

// ============ grouped GEMM2: 256 rows x 256 cols, BK=64, same pipeline ============
__global__ __launch_bounds__(512, 2)
void gemm2_kernel(const unsigned short* __restrict__ actB,
                  const unsigned short* __restrict__ actE,
                  const float* __restrict__ base_dn,
                  const float* __restrict__ exp_dn,
                  const int* __restrict__ tmap,
                  const int* __restrict__ list,
                  float* __restrict__ outB,
                  float* __restrict__ yslot) {
    __shared__ unsigned short lds_a[2][256 * 64];
    __shared__ unsigned short lds_b[2][256 * 64];
    __shared__ int s_row[256];
    __shared__ int sh[20];

    int tid = threadIdx.x;
    if (tid < 20) sh[tid] = tmap[tid];
    __syncthreads();
    int bid = blockIdx.x;
    int virt = (bid & 7) * 32 + (bid >> 3);      // 256 = 8*32; one col-strip per XCD
    int jcol = virt >> 5;                        // 0..7
    int rt = virt & 31;
    if (rt >= sh[9]) return;
    int g = 0;
    while (rt >= sh[g + 1]) ++g;
    int rows_g = sh[10 + g];
    int row0 = (rt - sh[g]) * 256;
    int n0 = jcol * 256;

    if (tid < 256) {
        int r = row0 + tid;
        int rowi = 0;
        if (r < rows_g) rowi = (g == 0) ? r : list[(g - 1) * TT + r];
        s_row[tid] = rowi;
    }
    __syncthreads();

    const unsigned short* abase = (g == 0) ? actB : actE;
    const float* W = (g == 0) ? base_dn : (exp_dn + (size_t)(g - 1) * IDIM * H);
    float* obase = (g == 0) ? outB : yslot;

    int arow_l = tid >> 3;
    int akc = tid & 7;
    int asw = akc ^ (arow_l & 7);
    const unsigned short* asrc[4];
#pragma unroll
    for (int i = 0; i < 4; ++i)
        asrc[i] = abase + (size_t)s_row[i * 64 + arow_l] * IDIM + asw * 8;
    int awoff = (tid >> 6) * 1024;

    auto issueA = [&](int ktile, int buf) {
#pragma unroll
        for (int i = 0; i < 4; ++i)
            gload_lds16(asrc[i] + ktile * 64, (char*)lds_a[buf] + i * 8192 + awoff);
    };

    int cg = tid & 63, kr = tid >> 6;
    int c0 = cg * 4;
    const float* wp = W + (size_t)kr * 8 * H + n0 + c0;
    int bwaddr[4];
#pragma unroll
    for (int j = 0; j < 4; ++j)
        bwaddr[j] = (c0 + j) * 128 + ((kr ^ ((c0 + j) & 7)) << 4);

    auto ldB = [&](float4* dst, int ktile) {
        const float* p = wp + (size_t)(ktile * 64) * H;
#pragma unroll
        for (int r = 0; r < 8; ++r)
            dst[r] = *reinterpret_cast<const float4*>(p + (size_t)r * H);
    };
    auto wrB = [&](const float4* src, int buf) {
        char* pb = (char*)lds_b[buf];
#pragma unroll
        for (int j = 0; j < 4; ++j) {
            uint4 pk;
            pk.x = pk2(((const float*)&src[0])[j], ((const float*)&src[1])[j]);
            pk.y = pk2(((const float*)&src[2])[j], ((const float*)&src[3])[j]);
            pk.z = pk2(((const float*)&src[4])[j], ((const float*)&src[5])[j]);
            pk.w = pk2(((const float*)&src[6])[j], ((const float*)&src[7])[j]);
            *reinterpret_cast<uint4*>(pb + bwaddr[j]) = pk;
        }
    };

    int wave = tid >> 6, lane = tid & 63;
    int wr = wave >> 2, wc = wave & 3;
    int arow0 = wr * 128 + (lane & 15);
    int bcol0 = wc * 64 + (lane & 15);
    int lxor = lane & 7;
    int kq = lane >> 4;

    f32x4 acc[8][4];
#pragma unroll
    for (int fm = 0; fm < 8; ++fm)
#pragma unroll
        for (int fn = 0; fn < 4; ++fn)
            acc[fm][fn] = (f32x4)(0.0f);

    auto mfmaTile = [&](int buf) {
        const char* pa = (const char*)lds_a[buf];
        const char* pb = (const char*)lds_b[buf];
#pragma unroll
        for (int kh = 0; kh < 2; ++kh) {
            int kc = kq + kh * 4;
            int slot = (kc ^ lxor) << 4;
            bf16x8 bfr[4];
#pragma unroll
            for (int fn = 0; fn < 4; ++fn)
                bfr[fn] = *reinterpret_cast<const bf16x8*>(pb + (bcol0 + fn * 16) * 128 + slot);
#pragma unroll
            for (int fmh = 0; fmh < 2; ++fmh) {
                bf16x8 afr[4];
#pragma unroll
                for (int i = 0; i < 4; ++i)
                    afr[i] = *reinterpret_cast<const bf16x8*>(
                        pa + (arow0 + fmh * 64 + i * 16) * 128 + slot);
#pragma unroll
                for (int fn = 0; fn < 4; ++fn)
#pragma unroll
                    for (int i = 0; i < 4; ++i)
                        acc[fmh * 4 + i][fn] = __builtin_amdgcn_mfma_f32_16x16x32_bf16(
                            afr[i], bfr[fn], acc[fmh * 4 + i][fn], 0, 0, 0);
            }
        }
    };

    float4 rB0[8], rB1[8];
    issueA(0, 0);
    ldB(rB0, 0);
    wrB(rB0, 0);
    ldB(rB1, 1);
    issueA(1, 1);
    WAITCNT_FENCE("s_waitcnt lgkmcnt(0)")

    for (int kt = 0; kt < NK2 - 2; kt += 2) {
        wrB(rB1, 1);
        ldB(rB0, kt + 2);
        mfmaTile(0);
        WAITCNT_FENCE("s_waitcnt vmcnt(8) lgkmcnt(0)")
        issueA(kt + 2, 0);
        wrB(rB0, 0);
        ldB(rB1, kt + 3);
        mfmaTile(1);
        WAITCNT_FENCE("s_waitcnt vmcnt(8) lgkmcnt(0)")
        issueA(kt + 3, 1);
    }
    wrB(rB1, 1);
    mfmaTile(0);
    WAITCNT_FENCE("s_waitcnt vmcnt(0) lgkmcnt(0)")
    mfmaTile(1);

    int cq = lane >> 4, cr = lane & 15;
#pragma unroll
    for (int fm = 0; fm < 8; ++fm) {
#pragma unroll
        for (int r = 0; r < 4; ++r) {
            int rloc = wr * 128 + fm * 16 + cq * 4 + r;
            if (row0 + rloc < rows_g) {
                size_t orow = (size_t)s_row[rloc];
#pragma unroll
                for (int fn = 0; fn < 4; ++fn) {
                    int col = n0 + wc * 64 + fn * 16 + cr;
                    obase[orow * H + col] = acc[fm][fn][r];
                }
            }
        }
    }
}

// ---------------- combine: out += w0*y0 + w1*y1 ----------------
__global__ void combine_kernel(float* __restrict__ out, const float* __restrict__ yslot,
                               const float* __restrict__ topw) {
    int i = blockIdx.x * blockDim.x + threadIdx.x;
    int t = i >> 9;
    int c = (i & 511) << 2;
    float w0 = topw[t * 2], w1 = topw[t * 2 + 1];
    float4 y0 = *reinterpret_cast<const float4*>(yslot + ((size_t)(2 * t) * H + c));
    float4 y1 = *reinterpret_cast<const float4*>(yslot + ((size_t)(2 * t + 1) * H + c));
    float4* po = reinterpret_cast<float4*>(out + ((size_t)t * H + c));
    float4 o = *po;
    o.x += w0 * y0.x + w1 * y1.x;
    o.y += w0 * y0.y + w1 * y1.y;
    o.z += w0 * y0.z + w1 * y1.z;
    o.w += w0 * y0.w + w1 * y1.w;
    *po = o;
}

extern "C" void kernel_launch(void* const* d_in, const int* in_sizes, int n_in,
                              void* d_out, int out_size, void* d_ws, size_t ws_size,
                              hipStream_t stream) {
    const float* x   = (const float*)d_in[0];
    const float* gw  = (const float*)d_in[1];
    const float* bgu = (const float*)d_in[2];
    const float* bdn = (const float*)d_in[3];
    const float* egu = (const float*)d_in[4];
    const float* edn = (const float*)d_in[5];
    float* out = (float*)d_out;
    char* ws = (char*)d_ws;

    unsigned short* xb   = (unsigned short*)(ws + 0);          //  8,388,608 B
    unsigned short* actB = (unsigned short*)(ws + 8388608);    // 23,068,672 B
    unsigned short* actE = (unsigned short*)(ws + 31457280);   // 46,137,344 B
    float* yslot         = (float*)(ws + 77594624);            // 33,554,432 B
    float* topw          = (float*)(ws + 111149056);
    int* cnt             = (int*)(ws + 111165440);
    int* list            = (int*)(ws + 111165696);
    int* tmap            = (int*)(ws + 111231232);

    hipMemsetAsync(cnt, 0, NE * sizeof(int), stream);
    cvt_x_kernel<<<4096, 256, 0, stream>>>(x, xb);
    router_kernel<<<TT, 64, 0, stream>>>(x, gw, topw, cnt, list);
    setup_kernel<<<1, 64, 0, stream>>>(cnt, tmap);
    // gemm1: 44 col-tiles x 32 row-tiles (worst case), 512-thread blocks
    gemm1_kernel<<<1408, 512, 0, stream>>>(xb, bgu, egu, tmap, list, actB, actE);
    // gemm2: 8 col-tiles x 32 row-tiles
    gemm2_kernel<<<256, 512, 0, stream>>>(actB, actE, bdn, edn, tmap, list, out, yslot);
    combine_kernel<<<4096, 256, 0, stream>>>(out, yslot, topw);
}

// Round 7
// 1105.987 us; speedup vs baseline: 1.0588x; 1.0588x over previous
//
#include <hip/hip_runtime.h>
#include <math.h>

#define H 2048
#define IDIM 5632
#define NE 8
#define TT 2048            // tokens = 2*1024
#define LDW1 (2 * IDIM)    // 11264
#define NK1 (H / 64)       // 32

typedef __bf16 bf16x8 __attribute__((ext_vector_type(8)));
typedef float f32x4 __attribute__((ext_vector_type(4)));

__device__ __forceinline__ unsigned short f2bf(float f) {
    unsigned int u = __builtin_bit_cast(unsigned int, f);
    u += 0x7FFFu + ((u >> 16) & 1u);   // round-to-nearest-even
    return (unsigned short)(u >> 16);
}

__device__ __forceinline__ unsigned int pk2(float a, float b) {
    __bf16 x = (__bf16)a, y = (__bf16)b;
    unsigned short lo = __builtin_bit_cast(unsigned short, x);
    unsigned short hi = __builtin_bit_cast(unsigned short, y);
    return (unsigned int)lo | ((unsigned int)hi << 16);
}

__device__ __forceinline__ void gload_lds16(const void* g, void* l) {
    __builtin_amdgcn_global_load_lds(
        (const __attribute__((address_space(1))) void*)g,
        (__attribute__((address_space(3))) void*)l, 16, 0, 0);
}

// ---------------- x (fp32) -> bf16 ----------------
__global__ void cvt_x_kernel(const float* __restrict__ x, unsigned short* __restrict__ xb) {
    int i = blockIdx.x * blockDim.x + threadIdx.x;
    float4 v = reinterpret_cast<const float4*>(x)[i];
    ushort4 o;
    o.x = f2bf(v.x); o.y = f2bf(v.y); o.z = f2bf(v.z); o.w = f2bf(v.w);
    reinterpret_cast<ushort4*>(xb)[i] = o;
}

// ---------------- weights: fp32 [K][N] -> bf16 [N][K] (per matrix) ----------------
__global__ __launch_bounds__(256)
void cvt_w_kernel(const float* __restrict__ src, unsigned short* __restrict__ dst,
                  int K, int N, int tilesPerMat) {
    __shared__ unsigned short tsh[64][72];
    int bid = blockIdx.x;
    int mat = bid / tilesPerMat;
    int tile = bid % tilesPerMat;
    int nbCount = N >> 6;
    int kb = tile / nbCount, nb = tile % nbCount;
    const float* s = src + (size_t)mat * K * N + (size_t)(kb << 6) * N + (nb << 6);
    unsigned short* d = dst + (size_t)mat * K * N + (size_t)(nb << 6) * K + (kb << 6);
    int tid = threadIdx.x;
    int kr = tid >> 4;
    int n4 = (tid & 15) << 2;
#pragma unroll
    for (int p = 0; p < 4; ++p) {
        int k = p * 16 + kr;
        float4 v = *reinterpret_cast<const float4*>(s + (size_t)k * N + n4);
        tsh[n4 + 0][k] = f2bf(v.x);
        tsh[n4 + 1][k] = f2bf(v.y);
        tsh[n4 + 2][k] = f2bf(v.z);
        tsh[n4 + 3][k] = f2bf(v.w);
    }
    __syncthreads();
    int n = tid >> 2;
    int kq = (tid & 3) << 4;
#pragma unroll
    for (int h = 0; h < 2; ++h) {
        uint4 v = *reinterpret_cast<const uint4*>(&tsh[n][kq + h * 8]);
        *reinterpret_cast<uint4*>(d + (size_t)n * K + kq + h * 8) = v;
    }
}

// ---------------- router: fp64 logits, softmax, top-2, lists ----------------
__global__ void router_kernel(const float* __restrict__ x, const float* __restrict__ gw,
                              float* __restrict__ topw, int* __restrict__ cnt,
                              int* __restrict__ list) {
    int t = blockIdx.x;
    int lane = threadIdx.x;
    const float* xt = x + (size_t)t * H;
    double acc[NE];
#pragma unroll
    for (int e = 0; e < NE; ++e) acc[e] = 0.0;
    for (int h = lane; h < H; h += 64) {
        float xv = xt[h];
#pragma unroll
        for (int e = 0; e < NE; ++e) acc[e] += (double)xv * (double)gw[e * H + h];
    }
#pragma unroll
    for (int e = 0; e < NE; ++e) {
#pragma unroll
        for (int off = 32; off > 0; off >>= 1)
            acc[e] += __shfl_xor(acc[e], off, 64);
    }
    if (lane == 0) {
        double mx = acc[0];
#pragma unroll
        for (int e = 1; e < NE; ++e) mx = acc[e] > mx ? acc[e] : mx;
        double ex[NE], s = 0.0;
#pragma unroll
        for (int e = 0; e < NE; ++e) { ex[e] = exp(acc[e] - mx); s += ex[e]; }
        int e0 = 0; double b0 = ex[0];
#pragma unroll
        for (int e = 1; e < NE; ++e) if (ex[e] > b0) { b0 = ex[e]; e0 = e; }
        int e1 = -1; double b1 = -1.0;
#pragma unroll
        for (int e = 0; e < NE; ++e) if (e != e0 && ex[e] > b1) { b1 = ex[e]; e1 = e; }
        float p0 = (float)(b0 / s), p1 = (float)(b1 / s);
        float w0 = p0 / (p0 + p1), w1 = p1 / (p0 + p1);
        topw[t * 2 + 0] = w0;
        topw[t * 2 + 1] = w1;
        int pos0 = atomicAdd(&cnt[e0], 1); list[e0 * TT + pos0] = t * 2 + 0;
        int pos1 = atomicAdd(&cnt[e1], 1); list[e1 * TT + pos1] = t * 2 + 1;
    }
}

// ---------------- tile maps: [0..19] 128-row tiles (gemm2), [20..39] 256-row (gemm1) ----
__global__ void setup_kernel(const int* __restrict__ cnt, int* __restrict__ tmap) {
    if (threadIdx.x == 0) {
        int a128 = 0, a256 = 0;
        tmap[0] = 0; tmap[20] = 0;
        for (int g = 0; g < 9; ++g) {
            int rows = (g == 0) ? TT : cnt[g - 1];
            tmap[10 + g] = rows;
            tmap[30 + g] = rows;
            a128 += (rows + 127) >> 7;
            a256 += (rows + 255) >> 8;
            tmap[g + 1] = a128;
            tmap[20 + g + 1] = a256;
        }
        tmap[19] = 0; tmap[39] = 0;
    }
}

// ============ grouped GEMM1: 256 rows x 256 wcols, BK=64, 2-phase counted vmcnt ======
// Both operands bf16 via global_load_lds (A gathered tokens, B = w1p [n][k]); zero
// in-loop VALU staging, zero ds_write. XOR-16B swizzle on both gload source and
// ds_read (r5-verified 0-conflict scheme).
__global__ __launch_bounds__(512)
void gemm1_kernel(const unsigned short* __restrict__ xb,
                  const unsigned short* __restrict__ w1p,
                  const int* __restrict__ tmap,
                  const int* __restrict__ list,
                  unsigned short* __restrict__ actB,
                  unsigned short* __restrict__ actE) {
    __shared__ unsigned short lds_a[2][256 * 64];
    __shared__ unsigned short lds_b[2][256 * 64];
    __shared__ int s_arow[256];
    __shared__ int s_orow[256];
    __shared__ int sh[20];

    int tid = threadIdx.x;
    if (tid < 20) sh[tid] = tmap[20 + tid];
    __syncthreads();
    int bid = blockIdx.x;
    int virt = (bid & 7) * 176 + (bid >> 3);     // 1408 = 8*176; jcol contiguous per XCD
    int jcol = virt >> 5;                        // 0..43
    int rt = virt & 31;
    if (rt >= sh[9]) return;
    int g = 0;
    while (rt >= sh[g + 1]) ++g;
    int rows_g = sh[10 + g];
    int row0 = (rt - sh[g]) * 256;
    int n0a = jcol * 128;                        // act-col base (128 act cols = 256 wcols)

    if (tid < 256) {
        int r = row0 + tid;
        int arow = 0, orow = 0;
        if (r < rows_g) {
            if (g == 0) { arow = r; orow = r; }
            else { int e = list[(g - 1) * TT + r]; arow = e >> 1; orow = e; }
        }
        s_arow[tid] = arow;
        s_orow[tid] = orow;
    }
    __syncthreads();

    const unsigned short* W = w1p + (size_t)g * ((size_t)LDW1 * H);
    unsigned short* actPtr = (g == 0) ? actB : actE;

    // staging: chunk = i*512+tid -> row/col = chunk>>3 (0..255), kc = chunk&7
    const unsigned short* asrc[4];
    const unsigned short* bsrc[4];
#pragma unroll
    for (int i = 0; i < 4; ++i) {
        int chunk = i * 512 + tid;
        int rl = chunk >> 3, kc = chunk & 7;
        asrc[i] = xb + (size_t)s_arow[rl] * H + ((kc ^ (rl & 7)) << 3);
        int wcol = ((rl >> 5) & 1 ? IDIM : 0) + n0a + ((rl >> 6) << 5) + (rl & 31);
        bsrc[i] = W + (size_t)wcol * H + ((kc ^ (rl & 7)) << 3);
    }
    int dstoff = (tid >> 6) * 1024;              // wave-uniform; HW adds lane*16

    auto issueAB = [&](int kt, int buf) {
#pragma unroll
        for (int i = 0; i < 4; ++i)
            gload_lds16(asrc[i] + kt * 64, (char*)lds_a[buf] + i * 8192 + dstoff);
#pragma unroll
        for (int i = 0; i < 4; ++i)
            gload_lds16(bsrc[i] + kt * 64, (char*)lds_b[buf] + i * 8192 + dstoff);
    };

    // MFMA geometry: 8 waves = 2M x 4N; per wave 128 rows x 64 cols
    int wave = tid >> 6, lane = tid & 63;
    int wr = wave >> 2, wc = wave & 3;
    int arow0 = wr * 128 + (lane & 15);
    int bcol0 = wc * 64 + (lane & 15);
    int lxor = lane & 7;
    int kq = lane >> 4;

    f32x4 acc[8][4];
#pragma unroll
    for (int fm = 0; fm < 8; ++fm)
#pragma unroll
        for (int fn = 0; fn < 4; ++fn)
            acc[fm][fn] = (f32x4)(0.0f);

    auto mfmaTile = [&](int buf) {
        const char* pa = (const char*)lds_a[buf];
        const char* pb = (const char*)lds_b[buf];
#pragma unroll
        for (int kh = 0; kh < 2; ++kh) {
            int kc = kq + kh * 4;
            int slot = (kc ^ lxor) << 4;
            bf16x8 bfr[4];
#pragma unroll
            for (int fn = 0; fn < 4; ++fn)
                bfr[fn] = *reinterpret_cast<const bf16x8*>(pb + (bcol0 + fn * 16) * 128 + slot);
#pragma unroll
            for (int fmh = 0; fmh < 2; ++fmh) {
                bf16x8 afr[4];
#pragma unroll
                for (int i = 0; i < 4; ++i)
                    afr[i] = *reinterpret_cast<const bf16x8*>(
                        pa + (arow0 + fmh * 64 + i * 16) * 128 + slot);
#pragma unroll
                for (int fn = 0; fn < 4; ++fn)
#pragma unroll
                    for (int i = 0; i < 4; ++i)
                        acc[fmh * 4 + i][fn] = __builtin_amdgcn_mfma_f32_16x16x32_bf16(
                            afr[i], bfr[fn], acc[fmh * 4 + i][fn], 0, 0, 0);
            }
        }
    };

    issueAB(0, 0);
    for (int t = 0; t < NK1; ++t) {
        int buf = t & 1;
        if (t + 1 < NK1) {
            issueAB(t + 1, buf ^ 1);
            asm volatile("s_waitcnt vmcnt(8)" ::: "memory");
        } else {
            asm volatile("s_waitcnt vmcnt(0)" ::: "memory");
        }
        __builtin_amdgcn_sched_barrier(0);
        __builtin_amdgcn_s_barrier();
        __builtin_amdgcn_sched_barrier(0);
        mfmaTile(buf);
        __builtin_amdgcn_sched_barrier(0);
        __builtin_amdgcn_s_barrier();
    }

    int cq = lane >> 4, cr = lane & 15;
#pragma unroll
    for (int fm = 0; fm < 8; ++fm) {
#pragma unroll
        for (int r = 0; r < 4; ++r) {
            int rloc = wr * 128 + fm * 16 + cq * 4 + r;
            if (row0 + rloc < rows_g) {
                size_t orow = (size_t)s_orow[rloc];
#pragma unroll
                for (int fn = 0; fn < 2; ++fn) {
                    float gv = acc[fm][fn][r];
                    float uv = acc[fm][fn + 2][r];
                    float sv = gv / (1.0f + __expf(-gv));
                    int col = n0a + wc * 32 + fn * 16 + cr;
                    actPtr[orow * IDIM + col] = f2bf(sv * uv);
                }
            }
        }
    }
}

// ============ grouped GEMM2: 128 rows x 128 cols, direct fp32 weights (r3-proven) =====
__global__ __launch_bounds__(256)
void gemm2_kernel(const unsigned short* __restrict__ actB,
                  const unsigned short* __restrict__ actE,
                  const float* __restrict__ base_dn,
                  const float* __restrict__ exp_dn,
                  const int* __restrict__ tmap,
                  const int* __restrict__ list,
                  float* __restrict__ outB,
                  float* __restrict__ yslot) {
    __shared__ unsigned short lds_a[128 * 64];
    __shared__ unsigned short lds_b[128 * 64];
    __shared__ int s_row[128];
    __shared__ int sh[20];

    int tid = threadIdx.x;
    if (tid < 20) sh[tid] = tmap[tid];
    __syncthreads();
    int id = blockIdx.x;
    int xcd = id & 7, sflat = id >> 3;
    int jcol = (sflat / 56) * 8 + xcd;
    int rt = sflat % 56;
    if (rt >= sh[9]) return;
    int g = 0;
    while (rt >= sh[g + 1]) ++g;
    int rows_g = sh[10 + g];
    int row0 = (rt - sh[g]) * 128;
    int n0 = jcol * 128;

    if (tid < 128) {
        int r = row0 + tid;
        int rowi = 0;
        if (r < rows_g) rowi = (g == 0) ? r : list[(g - 1) * TT + r];
        s_row[tid] = rowi;
    }
    __syncthreads();

    const unsigned short* abase = (g == 0) ? actB : actE;
    const float* W = (g == 0) ? base_dn : (exp_dn + (size_t)(g - 1) * IDIM * H);
    float* obase = (g == 0) ? outB : yslot;

    int arow_l = tid >> 3;
    int akc = tid & 7;
    int asw = akc ^ (arow_l & 7);
    const unsigned short* asrc[4];
#pragma unroll
    for (int i = 0; i < 4; ++i)
        asrc[i] = abase + (size_t)s_row[i * 32 + arow_l] * IDIM + asw * 8;
    char* adst = (char*)lds_a + (tid & 192) * 16;

    int cg = tid & 31;
    int kcB = tid >> 5;
    int c0 = cg * 4;
    const float* wp = W + n0 + c0 + (size_t)kcB * 8 * H;
    int bwaddr[4];
#pragma unroll
    for (int j = 0; j < 4; ++j)
        bwaddr[j] = (c0 + j) * 128 + ((kcB ^ ((c0 + j) & 7)) << 4);

    int wave = tid >> 6, lane = tid & 63;
    int wr = wave >> 1, wc = wave & 1;
    int arow_f = wr * 64 + (lane & 15);
    int bcol_f = wc * 64 + (lane & 15);
    int axor = arow_f & 7;
    int bxor = bcol_f & 7;
    int kq = lane >> 4;

    f32x4 acc[4][4];
#pragma unroll
    for (int fm = 0; fm < 4; ++fm)
#pragma unroll
        for (int fn = 0; fn < 4; ++fn)
            acc[fm][fn] = (f32x4)(0.0f);

    for (int k0 = 0; k0 < IDIM; k0 += 64) {
#pragma unroll
        for (int i = 0; i < 4; ++i)
            gload_lds16(asrc[i] + k0, adst + i * 4096);
        const float* wk = wp + (size_t)k0 * H;
        float bv[8][4];
#pragma unroll
        for (int r = 0; r < 8; ++r) {
            float4 t4 = *reinterpret_cast<const float4*>(wk + (size_t)r * H);
            bv[r][0] = t4.x; bv[r][1] = t4.y; bv[r][2] = t4.z; bv[r][3] = t4.w;
        }
#pragma unroll
        for (int j = 0; j < 4; ++j) {
            uint4 pk;
            pk.x = pk2(bv[0][j], bv[1][j]);
            pk.y = pk2(bv[2][j], bv[3][j]);
            pk.z = pk2(bv[4][j], bv[5][j]);
            pk.w = pk2(bv[6][j], bv[7][j]);
            *reinterpret_cast<uint4*>((char*)lds_b + bwaddr[j]) = pk;
        }
        __syncthreads();
#pragma unroll
        for (int ks = 0; ks < 2; ++ks) {
            int kc = kq + ks * 4;
            bf16x8 af[4];
#pragma unroll
            for (int fm = 0; fm < 4; ++fm)
                af[fm] = *reinterpret_cast<const bf16x8*>(
                    (char*)lds_a + (arow_f + fm * 16) * 128 + ((kc ^ axor) << 4));
#pragma unroll
            for (int fn = 0; fn < 4; ++fn) {
                bf16x8 bf = *reinterpret_cast<const bf16x8*>(
                    (char*)lds_b + (bcol_f + fn * 16) * 128 + ((kc ^ bxor) << 4));
#pragma unroll
                for (int fm = 0; fm < 4; ++fm)
                    acc[fm][fn] = __builtin_amdgcn_mfma_f32_16x16x32_bf16(
                        af[fm], bf, acc[fm][fn], 0, 0, 0);
            }
        }
        __syncthreads();
    }

    int cq = lane >> 4, cr = lane & 15;
#pragma unroll
    for (int fm = 0; fm < 4; ++fm) {
#pragma unroll
        for (int r = 0; r < 4; ++r) {
            int rloc = wr * 64 + fm * 16 + cq * 4 + r;
            if (row0 + rloc < rows_g) {
                size_t orow = (size_t)s_row[rloc];
#pragma unroll
                for (int fn = 0; fn < 4; ++fn) {
                    int col = n0 + wc * 64 + fn * 16 + cr;
                    obase[orow * H + col] = acc[fm][fn][r];
                }
            }
        }
    }
}

// ============ fallback GEMM1 (r3-proven, fp32 weights, 128 tile) ======================
__global__ __launch_bounds__(256)
void gemm1_fb(const unsigned short* __restrict__ xb,
              const float* __restrict__ base_gu,
              const float* __restrict__ exp_gu,
              const int* __restrict__ tmap,
              const int* __restrict__ list,
              unsigned short* __restrict__ actB,
              unsigned short* __restrict__ actE) {
    __shared__ unsigned short lds_a[128 * 64];
    __shared__ unsigned short lds_b[128 * 64];
    __shared__ int s_arow[128];
    __shared__ int s_orow[128];
    __shared__ int sh[20];

    int tid = threadIdx.x;
    if (tid < 20) sh[tid] = tmap[tid];
    __syncthreads();
    int id = blockIdx.x;
    int xcd = id & 7, sflat = id >> 3;
    int jcol = (sflat / 56) * 8 + xcd;
    int rt = sflat % 56;
    if (rt >= sh[9]) return;
    int g = 0;
    while (rt >= sh[g + 1]) ++g;
    int rows_g = sh[10 + g];
    int row0 = (rt - sh[g]) * 128;
    int n0 = jcol * 64;

    if (tid < 128) {
        int r = row0 + tid;
        int arow = 0, orow = 0;
        if (r < rows_g) {
            if (g == 0) { arow = r; orow = r; }
            else { int e = list[(g - 1) * TT + r]; arow = e >> 1; orow = e; }
        }
        s_arow[tid] = arow;
        s_orow[tid] = orow;
    }
    __syncthreads();

    const float* W = (g == 0) ? base_gu : (exp_gu + (size_t)(g - 1) * H * LDW1);
    unsigned short* actPtr = (g == 0) ? actB : actE;

    int arow_l = tid >> 3;
    int akc = tid & 7;
    int asw = akc ^ (arow_l & 7);
    const unsigned short* asrc[4];
#pragma unroll
    for (int i = 0; i < 4; ++i)
        asrc[i] = xb + (size_t)s_arow[i * 32 + arow_l] * H + asw * 8;
    char* adst = (char*)lds_a + (tid & 192) * 16;

    int cg = tid & 31;
    int kcB = tid >> 5;
    int c0 = cg * 4;
    int halfB = (c0 >> 5) & 1;
    int acol0 = n0 + ((c0 >> 6) << 5) + (c0 & 31);
    const float* wp = W + (size_t)(halfB ? IDIM : 0) + acol0 + (size_t)kcB * 8 * LDW1;
    int bwaddr[4];
#pragma unroll
    for (int j = 0; j < 4; ++j)
        bwaddr[j] = (c0 + j) * 128 + ((kcB ^ ((c0 + j) & 7)) << 4);

    int wave = tid >> 6, lane = tid & 63;
    int wr = wave >> 1, wc = wave & 1;
    int arow_f = wr * 64 + (lane & 15);
    int bcol_f = wc * 64 + (lane & 15);
    int axor = arow_f & 7;
    int bxor = bcol_f & 7;
    int kq = lane >> 4;

    f32x4 acc[4][4];
#pragma unroll
    for (int fm = 0; fm < 4; ++fm)
#pragma unroll
        for (int fn = 0; fn < 4; ++fn)
            acc[fm][fn] = (f32x4)(0.0f);

    for (int k0 = 0; k0 < H; k0 += 64) {
#pragma unroll
        for (int i = 0; i < 4; ++i)
            gload_lds16(asrc[i] + k0, adst + i * 4096);
        const float* wk = wp + (size_t)k0 * LDW1;
        float bv[8][4];
#pragma unroll
        for (int r = 0; r < 8; ++r) {
            float4 t4 = *reinterpret_cast<const float4*>(wk + (size_t)r * LDW1);
            bv[r][0] = t4.x; bv[r][1] = t4.y; bv[r][2] = t4.z; bv[r][3] = t4.w;
        }
#pragma unroll
        for (int j = 0; j < 4; ++j) {
            uint4 pk;
            pk.x = pk2(bv[0][j], bv[1][j]);
            pk.y = pk2(bv[2][j], bv[3][j]);
            pk.z = pk2(bv[4][j], bv[5][j]);
            pk.w = pk2(bv[6][j], bv[7][j]);
            *reinterpret_cast<uint4*>((char*)lds_b + bwaddr[j]) = pk;
        }
        __syncthreads();
#pragma unroll
        for (int ks = 0; ks < 2; ++ks) {
            int kc = kq + ks * 4;
            bf16x8 af[4];
#pragma unroll
            for (int fm = 0; fm < 4; ++fm)
                af[fm] = *reinterpret_cast<const bf16x8*>(
                    (char*)lds_a + (arow_f + fm * 16) * 128 + ((kc ^ axor) << 4));
#pragma unroll
            for (int fn = 0; fn < 4; ++fn) {
                bf16x8 bf = *reinterpret_cast<const bf16x8*>(
                    (char*)lds_b + (bcol_f + fn * 16) * 128 + ((kc ^ bxor) << 4));
#pragma unroll
                for (int fm = 0; fm < 4; ++fm)
                    acc[fm][fn] = __builtin_amdgcn_mfma_f32_16x16x32_bf16(
                        af[fm], bf, acc[fm][fn], 0, 0, 0);
            }
        }
        __syncthreads();
    }

    int cq = lane >> 4, cr = lane & 15;
#pragma unroll
    for (int fm = 0; fm < 4; ++fm) {
#pragma unroll
        for (int r = 0; r < 4; ++r) {
            int rloc = wr * 64 + fm * 16 + cq * 4 + r;
            if (row0 + rloc < rows_g) {
                size_t orow = (size_t)s_orow[rloc];
#pragma unroll
                for (int fn = 0; fn < 2; ++fn) {
                    float gv = acc[fm][fn][r];
                    float uv = acc[fm][fn + 2][r];
                    float sv = gv / (1.0f + __expf(-gv));
                    int col = n0 + wc * 32 + fn * 16 + cr;
                    actPtr[orow * IDIM + col] = f2bf(sv * uv);
                }
            }
        }
    }
}

// ---------------- combine: out += w0*y0 + w1*y1 ----------------
__global__ void combine_kernel(float* __restrict__ out, const float* __restrict__ yslot,
                               const float* __restrict__ topw) {
    int i = blockIdx.x * blockDim.x + threadIdx.x;
    int t = i >> 9;
    int c = (i & 511) << 2;
    float w0 = topw[t * 2], w1 = topw[t * 2 + 1];
    float4 y0 = *reinterpret_cast<const float4*>(yslot + ((size_t)(2 * t) * H + c));
    float4 y1 = *reinterpret_cast<const float4*>(yslot + ((size_t)(2 * t + 1) * H + c));
    float4* po = reinterpret_cast<float4*>(out + ((size_t)t * H + c));
    float4 o = *po;
    o.x += w0 * y0.x + w1 * y1.x;
    o.y += w0 * y0.y + w1 * y1.y;
    o.z += w0 * y0.z + w1 * y1.z;
    o.w += w0 * y0.w + w1 * y1.w;
    *po = o;
}

extern "C" void kernel_launch(void* const* d_in, const int* in_sizes, int n_in,
                              void* d_out, int out_size, void* d_ws, size_t ws_size,
                              hipStream_t stream) {
    const float* x   = (const float*)d_in[0];
    const float* gw  = (const float*)d_in[1];
    const float* bgu = (const float*)d_in[2];
    const float* bdn = (const float*)d_in[3];
    const float* egu = (const float*)d_in[4];
    const float* edn = (const float*)d_in[5];
    float* out = (float*)d_out;
    char* ws = (char*)d_ws;

    unsigned short* xb   = (unsigned short*)(ws + 0);          //  8,388,608 B
    unsigned short* actB = (unsigned short*)(ws + 8388608);    // 23,068,672 B
    unsigned short* actE = (unsigned short*)(ws + 31457280);   // 46,137,344 B
    float* yslot         = (float*)(ws + 77594624);            // 33,554,432 B
    float* topw          = (float*)(ws + 111149056);
    int* cnt             = (int*)(ws + 111165440);
    int* list            = (int*)(ws + 111165696);
    int* tmap            = (int*)(ws + 111231232);             // 48 ints
    unsigned short* w1p  = (unsigned short*)(ws + 111231488);  // 415,236,096 B
    const size_t NEED = 111231488ull + 415236096ull;           // 526,467,584

    hipMemsetAsync(cnt, 0, NE * sizeof(int), stream);
    cvt_x_kernel<<<4096, 256, 0, stream>>>(x, xb);
    router_kernel<<<TT, 64, 0, stream>>>(x, gw, topw, cnt, list);
    setup_kernel<<<1, 64, 0, stream>>>(cnt, tmap);

    if (ws_size >= NEED) {
        cvt_w_kernel<<<5632, 256, 0, stream>>>(bgu, w1p, H, LDW1, 5632);
        cvt_w_kernel<<<8 * 5632, 256, 0, stream>>>(egu, w1p + (size_t)LDW1 * H, H, LDW1, 5632);
        // 44 col-strips x 32 row-tiles, 512-thread 8-wave blocks
        gemm1_kernel<<<1408, 512, 0, stream>>>(xb, w1p, tmap, list, actB, actE);
    } else {
        gemm1_fb<<<4928, 256, 0, stream>>>(xb, bgu, egu, tmap, list, actB, actE);
    }
    gemm2_kernel<<<896, 256, 0, stream>>>(actB, actE, bdn, edn, tmap, list, out, yslot);
    combine_kernel<<<4096, 256, 0, stream>>>(out, yslot, topw);
}

// Round 8
// 1002.028 us; speedup vs baseline: 1.1686x; 1.1037x over previous
//
#include <hip/hip_runtime.h>
#include <math.h>

#define H 2048
#define IDIM 5632
#define NE 8
#define TT 2048            // tokens = 2*1024
#define LDW1 (2 * IDIM)    // 11264
#define NK1 (H / 64)       // 32
#define NK2 (IDIM / 64)    // 88

typedef __bf16 bf16x8 __attribute__((ext_vector_type(8)));
typedef float f32x4 __attribute__((ext_vector_type(4)));

__device__ __forceinline__ unsigned short f2bf(float f) {
    unsigned int u = __builtin_bit_cast(unsigned int, f);
    u += 0x7FFFu + ((u >> 16) & 1u);   // round-to-nearest-even
    return (unsigned short)(u >> 16);
}

// HW convert: compiler emits v_cvt_pk_bf16_f32 from paired casts (RTNE)
__device__ __forceinline__ unsigned int pk2(float a, float b) {
    __bf16 x = (__bf16)a, y = (__bf16)b;
    unsigned short lo = __builtin_bit_cast(unsigned short, x);
    unsigned short hi = __builtin_bit_cast(unsigned short, y);
    return (unsigned int)lo | ((unsigned int)hi << 16);
}

__device__ __forceinline__ void gload_lds16(const void* g, void* l) {
    __builtin_amdgcn_global_load_lds(
        (const __attribute__((address_space(1))) void*)g,
        (__attribute__((address_space(3))) void*)l, 16, 0, 0);
}

// phase fences (m201 8-phase template)
#define PH_PRE                                          \
    __builtin_amdgcn_s_barrier();                       \
    asm volatile("s_waitcnt lgkmcnt(0)" ::: "memory");  \
    __builtin_amdgcn_sched_barrier(0);                  \
    __builtin_amdgcn_s_setprio(1);
#define PH_POST                                         \
    __builtin_amdgcn_s_setprio(0);                      \
    __builtin_amdgcn_sched_barrier(0);                  \
    __builtin_amdgcn_s_barrier();

// ---------------- x (fp32) -> bf16 ----------------
__global__ void cvt_x_kernel(const float* __restrict__ x, unsigned short* __restrict__ xb) {
    int i = blockIdx.x * blockDim.x + threadIdx.x;
    float4 v = reinterpret_cast<const float4*>(x)[i];
    ushort4 o;
    o.x = f2bf(v.x); o.y = f2bf(v.y); o.z = f2bf(v.z); o.w = f2bf(v.w);
    reinterpret_cast<ushort4*>(xb)[i] = o;
}

// ---------------- router: fp64 logits, softmax, top-2, lists ----------------
__global__ void router_kernel(const float* __restrict__ x, const float* __restrict__ gw,
                              float* __restrict__ topw, int* __restrict__ cnt,
                              int* __restrict__ list) {
    int t = blockIdx.x;
    int lane = threadIdx.x;
    const float* xt = x + (size_t)t * H;
    double acc[NE];
#pragma unroll
    for (int e = 0; e < NE; ++e) acc[e] = 0.0;
    for (int h = lane; h < H; h += 64) {
        float xv = xt[h];
#pragma unroll
        for (int e = 0; e < NE; ++e) acc[e] += (double)xv * (double)gw[e * H + h];
    }
#pragma unroll
    for (int e = 0; e < NE; ++e) {
#pragma unroll
        for (int off = 32; off > 0; off >>= 1)
            acc[e] += __shfl_xor(acc[e], off, 64);
    }
    if (lane == 0) {
        double mx = acc[0];
#pragma unroll
        for (int e = 1; e < NE; ++e) mx = acc[e] > mx ? acc[e] : mx;
        double ex[NE], s = 0.0;
#pragma unroll
        for (int e = 0; e < NE; ++e) { ex[e] = exp(acc[e] - mx); s += ex[e]; }
        int e0 = 0; double b0 = ex[0];
#pragma unroll
        for (int e = 1; e < NE; ++e) if (ex[e] > b0) { b0 = ex[e]; e0 = e; }
        int e1 = -1; double b1 = -1.0;
#pragma unroll
        for (int e = 0; e < NE; ++e) if (e != e0 && ex[e] > b1) { b1 = ex[e]; e1 = e; }
        float p0 = (float)(b0 / s), p1 = (float)(b1 / s);
        float w0 = p0 / (p0 + p1), w1 = p1 / (p0 + p1);
        topw[t * 2 + 0] = w0;
        topw[t * 2 + 1] = w1;
        int pos0 = atomicAdd(&cnt[e0], 1); list[e0 * TT + pos0] = t * 2 + 0;
        int pos1 = atomicAdd(&cnt[e1], 1); list[e1 * TT + pos1] = t * 2 + 1;
    }
}

// ---------------- tile map (256-row tiles at [20..39]) ----------------
__global__ void setup_kernel(const int* __restrict__ cnt, int* __restrict__ tmap) {
    if (threadIdx.x == 0) {
        int a128 = 0, a256 = 0;
        tmap[0] = 0; tmap[20] = 0;
        for (int g = 0; g < 9; ++g) {
            int rows = (g == 0) ? TT : cnt[g - 1];
            tmap[10 + g] = rows;
            tmap[30 + g] = rows;
            a128 += (rows + 127) >> 7;
            a256 += (rows + 255) >> 8;
            tmap[g + 1] = a128;
            tmap[20 + g + 1] = a256;
        }
        tmap[19] = 0; tmap[39] = 0;
    }
}

// ============ grouped GEMM1: 256 rows x 256 wcols, BK=64, 8-phase, fold-convert =======
// A (bf16 gathered tokens) via global_load_lds; B (fp32 weights) loaded as 32 coalesced
// dwords -> cvt_pk -> conflict-free swizzled ds_write (write-late in P2/P3).
__global__ __launch_bounds__(512)
void gemm1_kernel(const unsigned short* __restrict__ xb,
                  const float* __restrict__ base_gu,
                  const float* __restrict__ exp_gu,
                  const int* __restrict__ tmap,
                  const int* __restrict__ list,
                  unsigned short* __restrict__ actB,
                  unsigned short* __restrict__ actE) {
    __shared__ unsigned short lds_a[2][256 * 64];
    __shared__ unsigned short lds_b[2][256 * 64];
    __shared__ int s_arow[256];
    __shared__ int s_orow[256];
    __shared__ int sh[20];

    int tid = threadIdx.x;
    if (tid < 20) sh[tid] = tmap[20 + tid];
    __syncthreads();
    int bid = blockIdx.x;
    int virt = (bid & 7) * 176 + (bid >> 3);     // 1408 = 8*176; jcols contiguous per XCD
    int jcol = virt >> 5;                        // 0..43
    int rt = virt & 31;
    if (rt >= sh[9]) return;
    int g = 0;
    while (rt >= sh[g + 1]) ++g;
    int rows_g = sh[10 + g];
    int row0 = (rt - sh[g]) * 256;
    int n0a = jcol * 128;                        // act-col base

    if (tid < 256) {
        int r = row0 + tid;
        int arow = 0, orow = 0;
        if (r < rows_g) {
            if (g == 0) { arow = r; orow = r; }
            else { int e = list[(g - 1) * TT + r]; arow = e >> 1; orow = e; }
        }
        s_arow[tid] = arow;
        s_orow[tid] = orow;
    }
    __syncthreads();

    const float* W = (g == 0) ? base_gu : (exp_gu + (size_t)(g - 1) * H * LDW1);
    unsigned short* actPtr = (g == 0) ? actB : actE;

    // ---- A staging sources (4 gloads/tile; chunk = i*512+tid -> row=chunk>>3, kc=chunk&7)
    const unsigned short* asrc[4];
#pragma unroll
    for (int i = 0; i < 4; ++i) {
        int chunk = i * 512 + tid;
        int rl = chunk >> 3, kc = chunk & 7;
        asrc[i] = xb + (size_t)s_arow[rl] * H + ((kc ^ (rl & 7)) << 3);
    }
    int dstoff = (tid >> 6) * 1024;

    // ---- B fp32 staging: ks = wave id (k-chunk), cb = lane; 4 spread cols c, c+64, ...
    int ks = tid >> 6, cb = tid & 63;
    const float* bp[4];
    int bwaddr[4];
#pragma unroll
    for (int j = 0; j < 4; ++j) {
        int rl = cb + 64 * j;                    // LDS col 0..255
        int wcol = (((rl >> 5) & 1) ? IDIM : 0) + n0a + ((rl >> 6) << 5) + (rl & 31);
        bp[j] = W + (size_t)(ks * 8) * LDW1 + wcol;
        bwaddr[j] = rl * 128 + ((ks ^ (cb & 7)) << 4);   // (rl&7)==(cb&7)
    }

    float br[8][4];
    auto ldB = [&](int kt, int rlo) {            // rows rlo..rlo+3, all 4 cols
#pragma unroll
        for (int r = 0; r < 4; ++r)
#pragma unroll
            for (int j = 0; j < 4; ++j)
                br[rlo + r][j] = bp[j][(size_t)(kt * 64 + rlo + r) * LDW1];
    };
    auto wrB = [&](int buf, int jlo) {           // chunks jlo, jlo+1
        char* pbw = (char*)lds_b[buf];
#pragma unroll
        for (int j = jlo; j < jlo + 2; ++j) {
            uint4 pk;
            pk.x = pk2(br[0][j], br[1][j]);
            pk.y = pk2(br[2][j], br[3][j]);
            pk.z = pk2(br[4][j], br[5][j]);
            pk.w = pk2(br[6][j], br[7][j]);
            *reinterpret_cast<uint4*>(pbw + bwaddr[j]) = pk;
        }
    };
    auto issueA = [&](int kt, int buf) {
#pragma unroll
        for (int i = 0; i < 4; ++i)
            gload_lds16(asrc[i] + kt * 64, (char*)lds_a[buf] + i * 8192 + dstoff);
    };

    // ---- MFMA geometry: 8 waves = 2M x 4N; per wave 128 rows x 64 cols
    int wave = tid >> 6, lane = tid & 63;
    int wr = wave >> 2, wc = wave & 3;
    int arow0 = wr * 128 + (lane & 15);
    int bcol0 = wc * 64 + (lane & 15);
    int lxor = lane & 7;
    int kq = lane >> 4;

    f32x4 acc[8][4];
#pragma unroll
    for (int fm = 0; fm < 8; ++fm)
#pragma unroll
        for (int fn = 0; fn < 4; ++fn)
            acc[fm][fn] = (f32x4)(0.0f);

    bf16x8 a0[4], a1[4], b0[4];
    auto rdA = [&](bf16x8* d, const char* pa, int slot, int fmh) {
#pragma unroll
        for (int i = 0; i < 4; ++i)
            d[i] = *reinterpret_cast<const bf16x8*>(pa + (arow0 + fmh * 64 + i * 16) * 128 + slot);
    };
    auto rdB = [&](bf16x8* d, const char* pb, int slot) {
#pragma unroll
        for (int fn = 0; fn < 4; ++fn)
            d[fn] = *reinterpret_cast<const bf16x8*>(pb + (bcol0 + fn * 16) * 128 + slot);
    };
    auto mf16 = [&](bf16x8* af, bf16x8* bf, int fmh) {
#pragma unroll
        for (int fn = 0; fn < 4; ++fn)
#pragma unroll
            for (int i = 0; i < 4; ++i)
                acc[fmh * 4 + i][fn] = __builtin_amdgcn_mfma_f32_16x16x32_bf16(
                    af[i], bf[fn], acc[fmh * 4 + i][fn], 0, 0, 0);
    };

    // prologue: stage tile 0 completely
    issueA(0, 0);
    ldB(0, 0); ldB(0, 4);
    wrB(0, 0); wrB(0, 2);
    asm volatile("s_waitcnt vmcnt(0)" ::: "memory");
    __builtin_amdgcn_sched_barrier(0);
    __builtin_amdgcn_s_barrier();
    __builtin_amdgcn_sched_barrier(0);

    for (int t = 0; t < NK1; ++t) {
        int buf = t & 1;
        const char* pa = (const char*)lds_a[buf];
        const char* pb = (const char*)lds_b[buf];
        bool pre = t + 1 < NK1;
        int slot0 = (kq ^ lxor) << 4;
        int slot1 = ((kq + 4) ^ lxor) << 4;
        // P0: kh0/fmh0; issue next A-gloads + first half of B fp32 loads
        rdB(b0, pb, slot0);
        rdA(a0, pa, slot0, 0);
        if (pre) { issueA(t + 1, buf ^ 1); ldB(t + 1, 0); }
        PH_PRE; mf16(a0, b0, 0); PH_POST;
        // P1: kh0/fmh1; second half of B loads
        rdA(a1, pa, slot0, 1);
        if (pre) ldB(t + 1, 4);
        PH_PRE; mf16(a1, b0, 1); PH_POST;
        // P2: kh1/fmh1; write-late B chunks 0-1
        rdB(b0, pb, slot1);
        rdA(a1, pa, slot1, 1);
        if (pre) wrB(buf ^ 1, 0);
        PH_PRE; mf16(a1, b0, 1); PH_POST;
        // P3: kh1/fmh0; write-late B chunks 2-3; tile-end vmcnt
        rdA(a0, pa, slot1, 0);
        if (pre) wrB(buf ^ 1, 2);
        __builtin_amdgcn_s_barrier();
        asm volatile("s_waitcnt lgkmcnt(0)" ::: "memory");
        __builtin_amdgcn_sched_barrier(0);
        __builtin_amdgcn_s_setprio(1);
        mf16(a0, b0, 0);
        __builtin_amdgcn_s_setprio(0);
        asm volatile("s_waitcnt vmcnt(0)" ::: "memory");
        __builtin_amdgcn_sched_barrier(0);
        __builtin_amdgcn_s_barrier();
        __builtin_amdgcn_sched_barrier(0);
    }

    int cq = lane >> 4, cr = lane & 15;
#pragma unroll
    for (int fm = 0; fm < 8; ++fm) {
#pragma unroll
        for (int r = 0; r < 4; ++r) {
            int rloc = wr * 128 + fm * 16 + cq * 4 + r;
            if (row0 + rloc < rows_g) {
                size_t orow = (size_t)s_orow[rloc];
#pragma unroll
                for (int fn = 0; fn < 2; ++fn) {
                    float gv = acc[fm][fn][r];
                    float uv = acc[fm][fn + 2][r];
                    float sv = gv / (1.0f + __expf(-gv));
                    int col = n0a + wc * 32 + fn * 16 + cr;
                    actPtr[orow * IDIM + col] = f2bf(sv * uv);
                }
            }
        }
    }
}

// ============ grouped GEMM2: 256 rows x 256 cols, BK=64, 8-phase, fold-convert ========
__global__ __launch_bounds__(512)
void gemm2_kernel(const unsigned short* __restrict__ actB,
                  const unsigned short* __restrict__ actE,
                  const float* __restrict__ base_dn,
                  const float* __restrict__ exp_dn,
                  const int* __restrict__ tmap,
                  const int* __restrict__ list,
                  float* __restrict__ outB,
                  float* __restrict__ yslot) {
    __shared__ unsigned short lds_a[2][256 * 64];
    __shared__ unsigned short lds_b[2][256 * 64];
    __shared__ int s_row[256];
    __shared__ int sh[20];

    int tid = threadIdx.x;
    if (tid < 20) sh[tid] = tmap[20 + tid];
    __syncthreads();
    int bid = blockIdx.x;
    int virt = (bid & 7) * 32 + (bid >> 3);      // 256 = 8*32; one col-strip per XCD
    int jcol = virt >> 5;                        // 0..7
    int rt = virt & 31;
    if (rt >= sh[9]) return;
    int g = 0;
    while (rt >= sh[g + 1]) ++g;
    int rows_g = sh[10 + g];
    int row0 = (rt - sh[g]) * 256;
    int n0 = jcol * 256;

    if (tid < 256) {
        int r = row0 + tid;
        int rowi = 0;
        if (r < rows_g) rowi = (g == 0) ? r : list[(g - 1) * TT + r];
        s_row[tid] = rowi;
    }
    __syncthreads();

    const unsigned short* abase = (g == 0) ? actB : actE;
    const float* W = (g == 0) ? base_dn : (exp_dn + (size_t)(g - 1) * IDIM * H);
    float* obase = (g == 0) ? outB : yslot;

    const unsigned short* asrc[4];
#pragma unroll
    for (int i = 0; i < 4; ++i) {
        int chunk = i * 512 + tid;
        int rl = chunk >> 3, kc = chunk & 7;
        asrc[i] = abase + (size_t)s_row[rl] * IDIM + ((kc ^ (rl & 7)) << 3);
    }
    int dstoff = (tid >> 6) * 1024;

    int ks = tid >> 6, cb = tid & 63;
    const float* bp[4];
    int bwaddr[4];
#pragma unroll
    for (int j = 0; j < 4; ++j) {
        int rl = cb + 64 * j;
        bp[j] = W + (size_t)(ks * 8) * H + n0 + rl;
        bwaddr[j] = rl * 128 + ((ks ^ (cb & 7)) << 4);
    }

    float br[8][4];
    auto ldB = [&](int kt, int rlo) {
#pragma unroll
        for (int r = 0; r < 4; ++r)
#pragma unroll
            for (int j = 0; j < 4; ++j)
                br[rlo + r][j] = bp[j][(size_t)(kt * 64 + rlo + r) * H];
    };
    auto wrB = [&](int buf, int jlo) {
        char* pbw = (char*)lds_b[buf];
#pragma unroll
        for (int j = jlo; j < jlo + 2; ++j) {
            uint4 pk;
            pk.x = pk2(br[0][j], br[1][j]);
            pk.y = pk2(br[2][j], br[3][j]);
            pk.z = pk2(br[4][j], br[5][j]);
            pk.w = pk2(br[6][j], br[7][j]);
            *reinterpret_cast<uint4*>(pbw + bwaddr[j]) = pk;
        }
    };
    auto issueA = [&](int kt, int buf) {
#pragma unroll
        for (int i = 0; i < 4; ++i)
            gload_lds16(asrc[i] + kt * 64, (char*)lds_a[buf] + i * 8192 + dstoff);
    };

    int wave = tid >> 6, lane = tid & 63;
    int wr = wave >> 2, wc = wave & 3;
    int arow0 = wr * 128 + (lane & 15);
    int bcol0 = wc * 64 + (lane & 15);
    int lxor = lane & 7;
    int kq = lane >> 4;

    f32x4 acc[8][4];
#pragma unroll
    for (int fm = 0; fm < 8; ++fm)
#pragma unroll
        for (int fn = 0; fn < 4; ++fn)
            acc[fm][fn] = (f32x4)(0.0f);

    bf16x8 a0[4], a1[4], b0[4];
    auto rdA = [&](bf16x8* d, const char* pa, int slot, int fmh) {
#pragma unroll
        for (int i = 0; i < 4; ++i)
            d[i] = *reinterpret_cast<const bf16x8*>(pa + (arow0 + fmh * 64 + i * 16) * 128 + slot);
    };
    auto rdB = [&](bf16x8* d, const char* pb, int slot) {
#pragma unroll
        for (int fn = 0; fn < 4; ++fn)
            d[fn] = *reinterpret_cast<const bf16x8*>(pb + (bcol0 + fn * 16) * 128 + slot);
    };
    auto mf16 = [&](bf16x8* af, bf16x8* bf, int fmh) {
#pragma unroll
        for (int fn = 0; fn < 4; ++fn)
#pragma unroll
            for (int i = 0; i < 4; ++i)
                acc[fmh * 4 + i][fn] = __builtin_amdgcn_mfma_f32_16x16x32_bf16(
                    af[i], bf[fn], acc[fmh * 4 + i][fn], 0, 0, 0);
    };

    issueA(0, 0);
    ldB(0, 0); ldB(0, 4);
    wrB(0, 0); wrB(0, 2);
    asm volatile("s_waitcnt vmcnt(0)" ::: "memory");
    __builtin_amdgcn_sched_barrier(0);
    __builtin_amdgcn_s_barrier();
    __builtin_amdgcn_sched_barrier(0);

    for (int t = 0; t < NK2; ++t) {
        int buf = t & 1;
        const char* pa = (const char*)lds_a[buf];
        const char* pb = (const char*)lds_b[buf];
        bool pre = t + 1 < NK2;
        int slot0 = (kq ^ lxor) << 4;
        int slot1 = ((kq + 4) ^ lxor) << 4;
        rdB(b0, pb, slot0);
        rdA(a0, pa, slot0, 0);
        if (pre) { issueA(t + 1, buf ^ 1); ldB(t + 1, 0); }
        PH_PRE; mf16(a0, b0, 0); PH_POST;
        rdA(a1, pa, slot0, 1);
        if (pre) ldB(t + 1, 4);
        PH_PRE; mf16(a1, b0, 1); PH_POST;
        rdB(b0, pb, slot1);
        rdA(a1, pa, slot1, 1);
        if (pre) wrB(buf ^ 1, 0);
        PH_PRE; mf16(a1, b0, 1); PH_POST;
        rdA(a0, pa, slot1, 0);
        if (pre) wrB(buf ^ 1, 2);
        __builtin_amdgcn_s_barrier();
        asm volatile("s_waitcnt lgkmcnt(0)" ::: "memory");
        __builtin_amdgcn_sched_barrier(0);
        __builtin_amdgcn_s_setprio(1);
        mf16(a0, b0, 0);
        __builtin_amdgcn_s_setprio(0);
        asm volatile("s_waitcnt vmcnt(0)" ::: "memory");
        __builtin_amdgcn_sched_barrier(0);
        __builtin_amdgcn_s_barrier();
        __builtin_amdgcn_sched_barrier(0);
    }

    int cq = lane >> 4, cr = lane & 15;
#pragma unroll
    for (int fm = 0; fm < 8; ++fm) {
#pragma unroll
        for (int r = 0; r < 4; ++r) {
            int rloc = wr * 128 + fm * 16 + cq * 4 + r;
            if (row0 + rloc < rows_g) {
                size_t orow = (size_t)s_row[rloc];
#pragma unroll
                for (int fn = 0; fn < 4; ++fn) {
                    int col = n0 + wc * 64 + fn * 16 + cr;
                    obase[orow * H + col] = acc[fm][fn][r];
                }
            }
        }
    }
}

// ---------------- combine: out += w0*y0 + w1*y1 ----------------
__global__ void combine_kernel(float* __restrict__ out, const float* __restrict__ yslot,
                               const float* __restrict__ topw) {
    int i = blockIdx.x * blockDim.x + threadIdx.x;
    int t = i >> 9;
    int c = (i & 511) << 2;
    float w0 = topw[t * 2], w1 = topw[t * 2 + 1];
    float4 y0 = *reinterpret_cast<const float4*>(yslot + ((size_t)(2 * t) * H + c));
    float4 y1 = *reinterpret_cast<const float4*>(yslot + ((size_t)(2 * t + 1) * H + c));
    float4* po = reinterpret_cast<float4*>(out + ((size_t)t * H + c));
    float4 o = *po;
    o.x += w0 * y0.x + w1 * y1.x;
    o.y += w0 * y0.y + w1 * y1.y;
    o.z += w0 * y0.z + w1 * y1.z;
    o.w += w0 * y0.w + w1 * y1.w;
    *po = o;
}

extern "C" void kernel_launch(void* const* d_in, const int* in_sizes, int n_in,
                              void* d_out, int out_size, void* d_ws, size_t ws_size,
                              hipStream_t stream) {
    const float* x   = (const float*)d_in[0];
    const float* gw  = (const float*)d_in[1];
    const float* bgu = (const float*)d_in[2];
    const float* bdn = (const float*)d_in[3];
    const float* egu = (const float*)d_in[4];
    const float* edn = (const float*)d_in[5];
    float* out = (float*)d_out;
    char* ws = (char*)d_ws;

    unsigned short* xb   = (unsigned short*)(ws + 0);          //  8,388,608 B
    unsigned short* actB = (unsigned short*)(ws + 8388608);    // 23,068,672 B
    unsigned short* actE = (unsigned short*)(ws + 31457280);   // 46,137,344 B
    float* yslot         = (float*)(ws + 77594624);            // 33,554,432 B
    float* topw          = (float*)(ws + 111149056);
    int* cnt             = (int*)(ws + 111165440);
    int* list            = (int*)(ws + 111165696);
    int* tmap            = (int*)(ws + 111231232);

    hipMemsetAsync(cnt, 0, NE * sizeof(int), stream);
    cvt_x_kernel<<<4096, 256, 0, stream>>>(x, xb);
    router_kernel<<<TT, 64, 0, stream>>>(x, gw, topw, cnt, list);
    setup_kernel<<<1, 64, 0, stream>>>(cnt, tmap);
    // gemm1: 44 col-strips x up-to-32 row-tiles, XCD-pinned
    gemm1_kernel<<<1408, 512, 0, stream>>>(xb, bgu, egu, tmap, list, actB, actE);
    // gemm2: 8 col-strips x up-to-32 row-tiles
    gemm2_kernel<<<256, 512, 0, stream>>>(actB, actE, bdn, edn, tmap, list, out, yslot);
    combine_kernel<<<4096, 256, 0, stream>>>(out, yslot, topw);
}